// Round 9
// baseline (17.251 us; speedup 1.0000x reference)
//
#include <hip/hip_runtime.h>

// InfoNCE loss, round 9: MSHR/latency falsification test.
// 2 batch rows per block (grid 1024): each thread gathers candidate c's
// ref row for BOTH rows -> 8 nt float4 gather loads in flight per thread
// (2x round 8). Waves 0 and 1 do the two logsumexps in parallel.

constexpr int BATCH = 2048;
constexpr int DIM   = 128;
constexpr int N_NEG = 63;
constexpr float TEMP_INV = 1.0f / 0.07f;
constexpr float EPSF = 1e-12f;

typedef float v4f __attribute__((ext_vector_type(4)));

__global__ __launch_bounds__(512) void infonce_partial(
    const float* __restrict__ q,       // [BATCH][DIM]
    const float* __restrict__ r,       // [VOCAB][DIM]
    const int*   __restrict__ pos,     // [BATCH]
    const int*   __restrict__ neg,     // [BATCH][N_NEG]
    float* __restrict__ partial)       // [BATCH]
{
    const int b0  = blockIdx.x * 2;      // rows b0, b0+1
    const int b1  = b0 + 1;
    const int tid = threadIdx.x;         // 0..511
    const int c   = tid >> 3;            // candidate 0..63 (0 = positive)
    const int t   = tid & 7;             // sub-lane within candidate

    int idx0 = (c == 0) ? pos[b0] : neg[(size_t)b0 * N_NEG + (c - 1)];
    int idx1 = (c == 0) ? pos[b1] : neg[(size_t)b1 * N_NEG + (c - 1)];

    const v4f* rrow0 = reinterpret_cast<const v4f*>(r + (size_t)idx0 * DIM);
    const v4f* rrow1 = reinterpret_cast<const v4f*>(r + (size_t)idx1 * DIM);
    const v4f* qrow0 = reinterpret_cast<const v4f*>(q + (size_t)b0 * DIM);
    const v4f* qrow1 = reinterpret_cast<const v4f*>(q + (size_t)b1 * DIM);

    // Issue all 8 gather loads (both rows) before any use.
    v4f rv0[4], rv1[4], qv0[4], qv1[4];
    #pragma unroll
    for (int j = 0; j < 4; ++j) rv0[j] = __builtin_nontemporal_load(&rrow0[t + 8 * j]);
    #pragma unroll
    for (int j = 0; j < 4; ++j) rv1[j] = __builtin_nontemporal_load(&rrow1[t + 8 * j]);
    #pragma unroll
    for (int j = 0; j < 4; ++j) qv0[j] = qrow0[t + 8 * j];
    #pragma unroll
    for (int j = 0; j < 4; ++j) qv1[j] = qrow1[t + 8 * j];

    float dot0 = 0.f, rn0 = 0.f, qn0 = 0.f;
    float dot1 = 0.f, rn1 = 0.f, qn1 = 0.f;
    #pragma unroll
    for (int j = 0; j < 4; ++j) {
        dot0 += qv0[j].x * rv0[j].x + qv0[j].y * rv0[j].y + qv0[j].z * rv0[j].z + qv0[j].w * rv0[j].w;
        rn0  += rv0[j].x * rv0[j].x + rv0[j].y * rv0[j].y + rv0[j].z * rv0[j].z + rv0[j].w * rv0[j].w;
        qn0  += qv0[j].x * qv0[j].x + qv0[j].y * qv0[j].y + qv0[j].z * qv0[j].z + qv0[j].w * qv0[j].w;
        dot1 += qv1[j].x * rv1[j].x + qv1[j].y * rv1[j].y + qv1[j].z * rv1[j].z + qv1[j].w * rv1[j].w;
        rn1  += rv1[j].x * rv1[j].x + rv1[j].y * rv1[j].y + rv1[j].z * rv1[j].z + rv1[j].w * rv1[j].w;
        qn1  += qv1[j].x * qv1[j].x + qv1[j].y * qv1[j].y + qv1[j].z * qv1[j].z + qv1[j].w * qv1[j].w;
    }

    #pragma unroll
    for (int d = 1; d <= 4; d <<= 1) {
        dot0 += __shfl_xor(dot0, d, 64);
        rn0  += __shfl_xor(rn0,  d, 64);
        qn0  += __shfl_xor(qn0,  d, 64);
        dot1 += __shfl_xor(dot1, d, 64);
        rn1  += __shfl_xor(rn1,  d, 64);
        qn1  += __shfl_xor(qn1,  d, 64);
    }

    float s0 = dot0 / (fmaxf(sqrtf(qn0), EPSF) * fmaxf(sqrtf(rn0), EPSF)) * TEMP_INV;
    float s1 = dot1 / (fmaxf(sqrtf(qn1), EPSF) * fmaxf(sqrtf(rn1), EPSF)) * TEMP_INV;

    __shared__ float sv[2][64];
    if (t == 0) { sv[0][c] = s0; sv[1][c] = s1; }
    __syncthreads();

    // waves 0 and 1 do the two 64-way logsumexps in parallel
    if (tid < 128) {
        const int row  = tid >> 6;           // 0 or 1
        const int lane = tid & 63;
        float x = sv[row][lane];
        float m = x;
        #pragma unroll
        for (int d = 32; d >= 1; d >>= 1) m = fmaxf(m, __shfl_xor(m, d, 64));
        float e = __expf(x - m);
        #pragma unroll
        for (int d = 32; d >= 1; d >>= 1) e += __shfl_xor(e, d, 64);
        if (lane == 0) {
            float lse = m + __logf(e);
            partial[b0 + row] = lse - sv[row][0];
        }
    }
}

__global__ __launch_bounds__(64) void infonce_reduce(
    const float* __restrict__ partial,   // [BATCH]
    float* __restrict__ out)             // [1]
{
    const int lane = threadIdx.x;        // 0..63, one wave
    const v4f* p4 = reinterpret_cast<const v4f*>(partial);

    v4f v[8];
    #pragma unroll
    for (int j = 0; j < 8; ++j) v[j] = p4[lane + 64 * j];

    float s = 0.0f;
    #pragma unroll
    for (int j = 0; j < 8; ++j) s += v[j].x + v[j].y + v[j].z + v[j].w;

    #pragma unroll
    for (int d = 32; d >= 1; d >>= 1) s += __shfl_xor(s, d, 64);

    if (lane == 0) out[0] = s * (1.0f / (float)BATCH);
}

extern "C" void kernel_launch(void* const* d_in, const int* in_sizes, int n_in,
                              void* d_out, int out_size, void* d_ws, size_t ws_size,
                              hipStream_t stream) {
    const float* q   = (const float*)d_in[0];
    const float* r   = (const float*)d_in[1];
    const int*   pos = (const int*)d_in[2];
    const int*   neg = (const int*)d_in[3];
    float* out     = (float*)d_out;
    float* partial = (float*)d_ws;       // 2048 floats, fully rewritten each call

    infonce_partial<<<dim3(BATCH / 2), dim3(512), 0, stream>>>(q, r, pos, neg, partial);
    infonce_reduce<<<dim3(1), dim3(64), 0, stream>>>(partial, out);
}